// Round 8
// baseline (282.002 us; speedup 1.0000x reference)
//
#include <hip/hip_runtime.h>
#include <hip/hip_cooperative_groups.h>

namespace cg = cooperative_groups;

#define A_TOT 8400
#define NCLS  80
#define MGT   64
#define TK    13
#define EPS7  1e-7f
#define EPS9  1e-9f
#define INV_PI2 0.4052847345693511f     // 4/pi^2

__device__ __forceinline__ float ciou_clip(
    float gx1, float gy1, float gx2, float gy2, float ga, float area1,
    float px1, float py1, float px2, float py2, float pa)
{
  float w2 = px2 - px1, h2 = py2 - py1 + EPS7;
  float iw = fmaxf(fminf(gx2, px2) - fmaxf(gx1, px1), 0.f);
  float ih = fmaxf(fminf(gy2, py2) - fmaxf(gy1, py1), 0.f);
  float inter = iw * ih;
  float uni = area1 + w2 * h2 - inter + EPS7;
  float iou = inter / uni;
  float cw = fmaxf(gx2, px2) - fminf(gx1, px1);
  float ch = fmaxf(gy2, py2) - fminf(gy1, py1);
  float c2 = cw * cw + ch * ch + EPS7;
  float dx = px1 + px2 - gx1 - gx2;
  float dy = py1 + py2 - gy1 - gy2;
  float rho2 = (dx * dx + dy * dy) * 0.25f;
  float dd = pa - ga;
  float v = INV_PI2 * dd * dd;
  float alpha = v / (v - iou + (1.f + EPS7));
  float c = iou - (rho2 / c2 + v * alpha);
  return fmaxf(c, 0.f);   // overlaps = ciou.clip(0)
}

__device__ __forceinline__ unsigned long long wmax64(unsigned long long k) {
#pragma unroll
  for (int s = 32; s > 0; s >>= 1) {
    unsigned long long o = __shfl_xor(k, s, 64);
    k = (o > k) ? o : k;
  }
  return k;
}

// ================= shared phase bodies (round-6 proven logic) =================

// Per-(b,m) top-13 via candidate rectangles; scatter bit m into mask64[b,a].
// Caller: 256 threads, block-uniform row. Early-returns (uniformly) if gt invalid.
__device__ __forceinline__ void topk_row_body(
    int row, int tid,
    const float* __restrict__ pd_scores,
    const float* __restrict__ pd_bboxes,
    const float2* __restrict__ anc2,
    const int* __restrict__ gt_labels,
    const float4* __restrict__ gb,
    const float* __restrict__ mask_gt,
    unsigned long long* __restrict__ mask64,
    unsigned long long* sk)             // shared, 4*TK
{
  if (mask_gt[row] <= 0.f) return;      // block-uniform
  int b = row >> 6;
  int m = row & 63;
  int lane = tid & 63, wid = tid >> 6;

  float4 g = gb[row];
  float ga = atanf((g.z - g.x) / (g.w - g.y + EPS7));
  float area1 = (g.z - g.x) * (g.w - g.y + EPS7);
  int label = gt_labels[row];
  const float*  ps = pd_scores + (size_t)b * A_TOT * NCLS + label;
  const float4* pb = (const float4*)(pd_bboxes + (size_t)b * A_TOT * 4);

  unsigned long long l[TK];
#pragma unroll
  for (int k = 0; k < TK; ++k) l[k] = 0ULL;

  auto insert = [&](unsigned long long key) {
    if (key > l[TK - 1]) {
#pragma unroll
      for (int j = TK - 1; j > 0; --j) {
        unsigned long long prev = l[j - 1];
        l[j] = (key > prev) ? prev : ((key > l[j]) ? key : l[j]);
      }
      l[0] = (key > l[0]) ? key : l[0];
    }
  };
  auto eval_inbox = [&](int a) -> unsigned long long {
    float4 p = pb[a];
    float pa = atanf((p.z - p.x) / (p.w - p.y + EPS7));
    float ov = ciou_clip(g.x, g.y, g.z, g.w, ga, area1, p.x, p.y, p.z, p.w, pa);
    float o2 = ov * ov;
    float metric = ps[(size_t)a * NCLS] * (o2 * o2 * o2);
    return (((unsigned long long)__float_as_uint(metric)) << 32) |
           (unsigned long long)(~(unsigned)a);
  };

  // pass 1: anchors 0..255 (zero-pool for tie-fills; covers rect cells < 256)
  {
    int a = tid;
    float2 an = anc2[a];
    float dmin = fminf(fminf(an.x - g.x, an.y - g.y), fminf(g.z - an.x, g.w - an.y));
    unsigned long long key = (unsigned long long)(~(unsigned)a);
    if (dmin > EPS9) key = eval_inbox(a);
    insert(key);
  }

  // pass 2: per-scale in-box rectangles (closed form; skip a<256)
  const int   ns[3] = {80, 40, 20};
  const float ss[3] = {8.f, 16.f, 32.f};
  const int   bb[3] = {0, 6400, 8000};
#pragma unroll
  for (int sc = 0; sc < 3; ++sc) {
    int n = ns[sc]; float s = ss[sc]; int base = bb[sc];
    float inv_s = 1.f / s;              // power of two: exact
    int xlo = max(0,     (int)floorf(g.x * inv_s - 0.5f));
    int xhi = min(n - 1, (int)ceilf (g.z * inv_s - 0.5f));
    int ylo = max(0,     (int)floorf(g.y * inv_s - 0.5f));
    int yhi = min(n - 1, (int)ceilf (g.w * inv_s - 0.5f));
    int nx = xhi - xlo + 1, ny = yhi - ylo + 1;
    if (nx <= 0 || ny <= 0) continue;
    int tot = nx * ny;
    float invnx = 1.f / (float)nx;
    for (int r = tid; r < tot; r += 256) {
      int q  = (int)floorf(((float)r + 0.5f) * invnx);
      int ix = xlo + (r - q * nx);
      int iy = ylo + q;
      int a = base + iy * n + ix;
      if (a < 256) continue;
      float ax = ((float)ix + 0.5f) * s;
      float ay = ((float)iy + 0.5f) * s;
      float dmin = fminf(fminf(ax - g.x, ay - g.y), fminf(g.z - ax, g.w - ay));
      if (dmin > EPS9) insert(eval_inbox(a));
      // out-of-box a>=256 never reaches top-13: 256 pass-1 keys dominate.
    }
  }

  // per-wave top-13 (keys unique: distinct ~a), cross-wave merge by wave 0
  unsigned long long wres = 0ULL;
#pragma unroll
  for (int r = 0; r < TK; ++r) {
    unsigned long long w = wmax64(l[0]);
    if (lane == r) wres = w;
    if (l[0] == w) {
#pragma unroll
      for (int j = 0; j < TK - 1; ++j) l[j] = l[j + 1];
      l[TK - 1] = 0ULL;
    }
  }
  if (lane < TK) sk[wid * TK + lane] = wres;
  __syncthreads();

  if (wid == 0) {
    unsigned long long c = (lane < 4 * TK) ? sk[lane] : 0ULL;
    unsigned long long res = 0ULL;
#pragma unroll
    for (int r = 0; r < TK; ++r) {
      unsigned long long w = wmax64(c);
      if (lane == r) res = w;
      if (c == w) c = 0ULL;
    }
    if (lane < TK) {
      unsigned a = ~(unsigned)res;
      float2 an = anc2[a];
      float dmin = fminf(fminf(an.x - g.x, an.y - g.y), fminf(g.z - an.x, g.w - an.y));
      if (dmin > EPS9)                  // mask_topk * mask_in_gts * mask_gt
        atomicOr(mask64 + (size_t)b * A_TOT + a, 1ULL << m);
    }
  }
}

// Per-anchor resolve: bg -> -1; single gt inline; multi gt -> whole-wave
// cooperative argmax (64 lanes <-> 64 gts), first-max via (fbits(ov)<<6)|(63-m).
__device__ __forceinline__ void resolve_body(
    int t, bool valid,
    const float* __restrict__ pd_scores,
    const float* __restrict__ pd_bboxes,
    const int* __restrict__ gt_labels,
    const float4* __restrict__ gb,
    const unsigned long long* __restrict__ mask64,
    int* __restrict__ tgt_ws, float* __restrict__ am_ws,
    unsigned int* __restrict__ pos_al, unsigned int* __restrict__ pos_ov)
{
  int lane = threadIdx.x & 63;
  unsigned long long msk = valid ? mask64[t] : 0ULL;
  int pc = __popcll(msk);
  float4 p = make_float4(0.f, 0.f, 0.f, 0.f);
  float pa_own = 0.f;
  if (valid && pc >= 1) {
    p = ((const float4*)pd_bboxes)[t];
    pa_own = atanf((p.z - p.x) / (p.w - p.y + EPS7));
  }
  if (valid && pc == 0) tgt_ws[t] = -1;
  if (valid && pc == 1) {
    int b = t / A_TOT;
    int tgt = __ffsll(msk) - 1;
    int gi = b * MGT + tgt;
    float4 g = gb[gi];
    float ga = atanf((g.z - g.x) / (g.w - g.y + EPS7));
    float area1 = (g.z - g.x) * (g.w - g.y + EPS7);
    float ov = ciou_clip(g.x, g.y, g.z, g.w, ga, area1,
                         p.x, p.y, p.z, p.w, pa_own);
    int label = gt_labels[gi];
    float sc = pd_scores[(size_t)t * NCLS + label];
    float o2 = ov * ov;
    float am = sc * (o2 * o2 * o2);
    tgt_ws[t] = tgt; am_ws[t] = am;
    atomicMax(pos_al + gi, __float_as_uint(am));
    atomicMax(pos_ov + gi, __float_as_uint(ov));
  }
  unsigned long long mb = __ballot(valid && pc > 1);
  while (mb) {
    int src = __ffsll(mb) - 1; mb &= mb - 1;
    int   tt  = __shfl(t, src);
    float px1 = __shfl(p.x, src), py1 = __shfl(p.y, src);
    float px2 = __shfl(p.z, src), py2 = __shfl(p.w, src);
    float pa  = __shfl(pa_own, src);
    int bb2 = tt / A_TOT;
    int gi = bb2 * MGT + lane;
    float4 g = gb[gi];
    float ga = atanf((g.z - g.x) / (g.w - g.y + EPS7));
    float area1 = (g.z - g.x) * (g.w - g.y + EPS7);
    float ov = ciou_clip(g.x, g.y, g.z, g.w, ga, area1,
                         px1, py1, px2, py2, pa);
    unsigned long long key =
        (((unsigned long long)__float_as_uint(ov)) << 6) | (unsigned)(63 - lane);
    unsigned long long w = wmax64(key);
    if (key == w) {                     // winner lane = argmax gt (first-max)
      int label = gt_labels[gi];
      float sc = pd_scores[(size_t)tt * NCLS + label];
      float o2 = ov * ov;
      float am = sc * (o2 * o2 * o2);
      tgt_ws[tt] = lane; am_ws[tt] = am;
      atomicMax(pos_al + gi, __float_as_uint(am));
      atomicMax(pos_ov + gi, __float_as_uint(ov));
    }
  }
}

// One 256-row output tile: per-row scalars + LDS-staged coalesced float4 scores.
__device__ __forceinline__ void write_body(
    int base, int tid, int total,
    const int* __restrict__ tgt_ws, const float* __restrict__ am_ws,
    const unsigned int* __restrict__ pos_al,
    const unsigned int* __restrict__ pos_ov,
    const int* __restrict__ gt_labels, const float4* __restrict__ gb,
    float* __restrict__ out, int* slab, float* snorm)
{
  int t = base + tid;
  int nrows = total - base; if (nrows > 256) nrows = 256;
  size_t OFF_BOX = (size_t)total;
  size_t OFF_SCR = OFF_BOX + (size_t)total * 4;
  size_t OFF_FG  = OFF_SCR + (size_t)total * NCLS;
  size_t OFF_TGT = OFF_FG + (size_t)total;
  int lab = 0; float nrm = 0.f;
  if (t < total) {
    int b = t / A_TOT;
    int tw = tgt_ws[t];
    bool fg = tw >= 0;
    int tgt = fg ? tw : 0;
    int gi = b * MGT + tgt;
    lab = gt_labels[gi]; if (lab < 0) lab = 0;
    float4 box = gb[gi];
    if (fg) {
      float pa_ = __uint_as_float(pos_al[gi]);
      float po  = __uint_as_float(pos_ov[gi]);
      nrm = am_ws[t] * po / (pa_ + EPS9);
    }
    out[t] = (float)lab;
    ((float4*)(out + OFF_BOX))[t] = box;
    out[OFF_FG + t]  = fg ? 1.f : 0.f;
    out[OFF_TGT + t] = (float)tgt;
  }
  slab[tid]  = lab;
  snorm[tid] = nrm;
  __syncthreads();
  float4* srow = (float4*)(out + OFF_SCR + (size_t)base * NCLS);
  int nvec = nrows * (NCLS / 4);
  for (int u = tid; u < nvec; u += 256) {
    int i  = u / (NCLS / 4);
    int c0 = (u - i * (NCLS / 4)) * 4;
    int lb = slab[i]; float nv = snorm[i];
    float4 v;
    v.x = (lb == c0    ) ? nv : 0.f;
    v.y = (lb == c0 + 1) ? nv : 0.f;
    v.z = (lb == c0 + 2) ? nv : 0.f;
    v.w = (lb == c0 + 3) ? nv : 0.f;
    srow[u] = v;
  }
}

// ===================== fused cooperative kernel =====================
__global__ __launch_bounds__(256)
void k_fused(const float* __restrict__ pd_scores,
             const float* __restrict__ pd_bboxes,
             const float* __restrict__ anc,
             const int* __restrict__ gt_labels,
             const float* __restrict__ gt_bboxes,
             const float* __restrict__ mask_gt,
             unsigned long long* __restrict__ mask64,
             unsigned int* __restrict__ pos_al,
             unsigned int* __restrict__ pos_ov,
             int* __restrict__ tgt_ws, float* __restrict__ am_ws,
             float* __restrict__ out, int bs)
{
  cg::grid_group grid = cg::this_grid();
  const int NA = bs * A_TOT, NM = bs * MGT;
  const int gsize = gridDim.x * 256;
  const int gtid = blockIdx.x * 256 + threadIdx.x;
  const int tid = threadIdx.x;

  __shared__ unsigned long long sk[4 * TK];
  __shared__ int   slab[256];
  __shared__ float snorm[256];

  const float2* anc2 = (const float2*)anc;
  const float4* gb   = (const float4*)gt_bboxes;

  // phase 0: zero accumulators (pos_al|pos_ov contiguous)
  for (int i = gtid; i < NA; i += gsize) mask64[i] = 0ULL;
  for (int i = gtid; i < 2 * NM; i += gsize) pos_al[i] = 0u;
  grid.sync();

  // phase 1: top-13 scatter (grid-stride over rows)
  for (int row = blockIdx.x; row < NM; row += gridDim.x) {
    topk_row_body(row, tid, pd_scores, pd_bboxes, anc2, gt_labels, gb,
                  mask_gt, mask64, sk);
    __syncthreads();                    // protect sk before next row
  }
  grid.sync();

  // phase 2: resolve (grid-stride over anchors; uniform trip count)
  for (int t0 = 0; t0 < NA; t0 += gsize) {
    int t = t0 + gtid;
    resolve_body(t, t < NA, pd_scores, pd_bboxes, gt_labels, gb, mask64,
                 tgt_ws, am_ws, pos_al, pos_ov);
  }
  grid.sync();

  // phase 3: outputs (grid-stride over 256-row tiles)
  int ntiles = (NA + 255) >> 8;
  for (int tile = blockIdx.x; tile < ntiles; tile += gridDim.x) {
    write_body(tile << 8, tid, NA, tgt_ws, am_ws, pos_al, pos_ov,
               gt_labels, gb, out, slab, snorm);
    __syncthreads();                    // protect slab/snorm before next tile
  }
}

// ===================== fallback standalone kernels =====================
__global__ __launch_bounds__(256)
void k_topk_sa(const float* __restrict__ pd_scores,
               const float* __restrict__ pd_bboxes,
               const float* __restrict__ anc,
               const int* __restrict__ gt_labels,
               const float* __restrict__ gt_bboxes,
               const float* __restrict__ mask_gt,
               unsigned long long* __restrict__ mask64)
{
  __shared__ unsigned long long sk[4 * TK];
  topk_row_body(blockIdx.x, threadIdx.x, pd_scores, pd_bboxes,
                (const float2*)anc, gt_labels, (const float4*)gt_bboxes,
                mask_gt, mask64, sk);
}

__global__ __launch_bounds__(256)
void k_resolve_sa(const float* __restrict__ pd_scores,
                  const float* __restrict__ pd_bboxes,
                  const int* __restrict__ gt_labels,
                  const float* __restrict__ gt_bboxes,
                  const unsigned long long* __restrict__ mask64,
                  int* __restrict__ tgt_ws, float* __restrict__ am_ws,
                  unsigned int* __restrict__ pos_al,
                  unsigned int* __restrict__ pos_ov, int total)
{
  int t = blockIdx.x * 256 + threadIdx.x;
  resolve_body(t, t < total, pd_scores, pd_bboxes, gt_labels,
               (const float4*)gt_bboxes, mask64, tgt_ws, am_ws, pos_al, pos_ov);
}

__global__ __launch_bounds__(256)
void k_write_sa(const int* __restrict__ tgt_ws, const float* __restrict__ am_ws,
                const unsigned int* __restrict__ pos_al,
                const unsigned int* __restrict__ pos_ov,
                const int* __restrict__ gt_labels,
                const float* __restrict__ gt_bboxes,
                float* __restrict__ out, int total)
{
  __shared__ int   slab[256];
  __shared__ float snorm[256];
  write_body(blockIdx.x * 256, threadIdx.x, total, tgt_ws, am_ws, pos_al,
             pos_ov, gt_labels, (const float4*)gt_bboxes, out, slab, snorm);
}

extern "C" void kernel_launch(void* const* d_in, const int* in_sizes, int n_in,
                              void* d_out, int out_size, void* d_ws, size_t ws_size,
                              hipStream_t stream)
{
  const float* pd_scores = (const float*)d_in[0];
  const float* pd_bboxes = (const float*)d_in[1];
  const float* anc       = (const float*)d_in[2];
  const int*   gt_labels = (const int*)d_in[3];
  const float* gt_bboxes = (const float*)d_in[4];
  const float* mask_gt   = (const float*)d_in[5];
  int bs = in_sizes[0] / (A_TOT * NCLS);
  int NA = bs * A_TOT, NM = bs * MGT;

  unsigned long long* mask64 = (unsigned long long*)d_ws;  // NA
  unsigned int* pos_al = (unsigned int*)(mask64 + NA);     // NM
  unsigned int* pos_ov = pos_al + NM;                      // NM (contig w/ al)
  int*   tgt_ws = (int*)(pos_ov + NM);                     // NA
  float* am_ws  = (float*)(tgt_ws + NA);                   // NA
  float* out = (float*)d_out;

  // try the single cooperative dispatch, sized by a real occupancy query
  hipError_t lerr = hipErrorUnknown;
  int blocksPerCU = 0;
  hipError_t qerr = hipOccupancyMaxActiveBlocksPerMultiprocessor(
      &blocksPerCU, k_fused, 256, 0);
  if (qerr == hipSuccess && blocksPerCU > 0) {
    int G = blocksPerCU * 256;          // 256 CUs on MI355X (gfx950)
    int need = (NA + 255) / 256; if (need < NM) need = NM;
    if (G > need) G = need;
    void* args[] = {
      (void*)&pd_scores, (void*)&pd_bboxes, (void*)&anc, (void*)&gt_labels,
      (void*)&gt_bboxes, (void*)&mask_gt, (void*)&mask64, (void*)&pos_al,
      (void*)&pos_ov, (void*)&tgt_ws, (void*)&am_ws, (void*)&out, (void*)&bs
    };
    lerr = hipLaunchCooperativeKernel((void*)k_fused, dim3(G), dim3(256),
                                      args, 0, stream);
  }

  if (lerr != hipSuccess) {
    // proven multi-dispatch path (round 6)
    hipMemsetAsync(mask64, 0, (size_t)NA * 8 + (size_t)NM * 8, stream);
    k_topk_sa<<<NM, 256, 0, stream>>>(pd_scores, pd_bboxes, anc, gt_labels,
                                      gt_bboxes, mask_gt, mask64);
    k_resolve_sa<<<(NA + 255) / 256, 256, 0, stream>>>(pd_scores, pd_bboxes,
                                                       gt_labels, gt_bboxes,
                                                       mask64, tgt_ws, am_ws,
                                                       pos_al, pos_ov, NA);
    k_write_sa<<<(NA + 255) / 256, 256, 0, stream>>>(tgt_ws, am_ws, pos_al,
                                                     pos_ov, gt_labels,
                                                     gt_bboxes, out, NA);
  }
}

// Round 9
// 137.415 us; speedup vs baseline: 2.0522x; 2.0522x over previous
//
#include <hip/hip_runtime.h>

#define A_TOT 8400
#define NCLS  80
#define MGT   64
#define TK    13
#define EPS7  1e-7f
#define EPS9  1e-9f
#define INV_PI2 0.4052847345693511f     // 4/pi^2
#define BTH   1024                      // k_resolveB block size
#define NIT   ((A_TOT + BTH - 1) / BTH) // 9 static sweep iterations

__device__ __forceinline__ float ciou_clip(
    float gx1, float gy1, float gx2, float gy2, float ga, float area1,
    float px1, float py1, float px2, float py2, float pa)
{
  float w2 = px2 - px1, h2 = py2 - py1 + EPS7;
  float iw = fmaxf(fminf(gx2, px2) - fmaxf(gx1, px1), 0.f);
  float ih = fmaxf(fminf(gy2, py2) - fmaxf(gy1, py1), 0.f);
  float inter = iw * ih;
  float uni = area1 + w2 * h2 - inter + EPS7;
  float iou = inter / uni;
  float cw = fmaxf(gx2, px2) - fminf(gx1, px1);
  float ch = fmaxf(gy2, py2) - fminf(gy1, py1);
  float c2 = cw * cw + ch * ch + EPS7;
  float dx = px1 + px2 - gx1 - gx2;
  float dy = py1 + py2 - gy1 - gy2;
  float rho2 = (dx * dx + dy * dy) * 0.25f;
  float dd = pa - ga;
  float v = INV_PI2 * dd * dd;
  float alpha = v / (v - iou + (1.f + EPS7));
  float c = iou - (rho2 / c2 + v * alpha);
  return fmaxf(c, 0.f);   // overlaps = ciou.clip(0)
}

__device__ __forceinline__ unsigned long long wmax64(unsigned long long k) {
#pragma unroll
  for (int s = 32; s > 0; s >>= 1) {
    unsigned long long o = __shfl_xor(k, s, 64);
    k = (o > k) ? o : k;
  }
  return k;
}

// ============ Node A: per-(b,m) top-13 -> dense index lists ============
// Candidate set = {anchors 0..255} U {in-box grid rectangles per scale}
// (provably contains lax.top_k(metrics,13); see round-5 argument). Every
// row writes all 13 slots (anchor id, or -1 if invalid gt / out-of-box
// winner) -> NO pre-zeroed memory needed anywhere.
__global__ __launch_bounds__(256)
void k_topkA(const float* __restrict__ pd_scores,
             const float* __restrict__ pd_bboxes,
             const float* __restrict__ anc,
             const int* __restrict__ gt_labels,
             const float* __restrict__ gt_bboxes,
             const float* __restrict__ mask_gt,
             int* __restrict__ topk_idx)
{
  int row = blockIdx.x;                 // b*MGT + m
  int tid = threadIdx.x, lane = tid & 63, wid = tid >> 6;
  __shared__ unsigned long long sk[4 * TK];

  if (mask_gt[row] <= 0.f) {            // block-uniform
    if (tid < TK) topk_idx[row * TK + tid] = -1;
    return;
  }
  int b = row >> 6;

  float4 g = ((const float4*)gt_bboxes)[row];
  float ga = atanf((g.z - g.x) / (g.w - g.y + EPS7));
  float area1 = (g.z - g.x) * (g.w - g.y + EPS7);
  int label = gt_labels[row];
  const float*  ps   = pd_scores + (size_t)b * A_TOT * NCLS + label;
  const float4* pb   = (const float4*)(pd_bboxes + (size_t)b * A_TOT * 4);
  const float2* anc2 = (const float2*)anc;

  unsigned long long l[TK];
#pragma unroll
  for (int k = 0; k < TK; ++k) l[k] = 0ULL;

  auto insert = [&](unsigned long long key) {
    if (key > l[TK - 1]) {
#pragma unroll
      for (int j = TK - 1; j > 0; --j) {
        unsigned long long prev = l[j - 1];
        l[j] = (key > prev) ? prev : ((key > l[j]) ? key : l[j]);
      }
      l[0] = (key > l[0]) ? key : l[0];
    }
  };
  auto eval_inbox = [&](int a) -> unsigned long long {
    float4 p = pb[a];
    float pa = atanf((p.z - p.x) / (p.w - p.y + EPS7));
    float ov = ciou_clip(g.x, g.y, g.z, g.w, ga, area1, p.x, p.y, p.z, p.w, pa);
    float o2 = ov * ov;
    float metric = ps[(size_t)a * NCLS] * (o2 * o2 * o2);
    return (((unsigned long long)__float_as_uint(metric)) << 32) |
           (unsigned long long)(~(unsigned)a);
  };

  // pass 1: anchors 0..255 (zero-pool for tie-fills; covers rect cells < 256)
  {
    int a = tid;
    float2 an = anc2[a];
    float dmin = fminf(fminf(an.x - g.x, an.y - g.y), fminf(g.z - an.x, g.w - an.y));
    unsigned long long key = (unsigned long long)(~(unsigned)a);
    if (dmin > EPS9) key = eval_inbox(a);
    insert(key);
  }

  // pass 2: per-scale in-box rectangles (closed form; skip a<256)
  const int   ns[3] = {80, 40, 20};
  const float ss[3] = {8.f, 16.f, 32.f};
  const int   bb[3] = {0, 6400, 8000};
#pragma unroll
  for (int sc = 0; sc < 3; ++sc) {
    int n = ns[sc]; float s = ss[sc]; int base = bb[sc];
    float inv_s = 1.f / s;              // power of two: exact
    int xlo = max(0,     (int)floorf(g.x * inv_s - 0.5f));
    int xhi = min(n - 1, (int)ceilf (g.z * inv_s - 0.5f));
    int ylo = max(0,     (int)floorf(g.y * inv_s - 0.5f));
    int yhi = min(n - 1, (int)ceilf (g.w * inv_s - 0.5f));
    int nx = xhi - xlo + 1, ny = yhi - ylo + 1;
    if (nx <= 0 || ny <= 0) continue;
    int tot = nx * ny;
    float invnx = 1.f / (float)nx;
    for (int r = tid; r < tot; r += 256) {
      int q  = (int)floorf(((float)r + 0.5f) * invnx);
      int ix = xlo + (r - q * nx);
      int iy = ylo + q;
      int a = base + iy * n + ix;
      if (a < 256) continue;
      float ax = ((float)ix + 0.5f) * s;
      float ay = ((float)iy + 0.5f) * s;
      float dmin = fminf(fminf(ax - g.x, ay - g.y), fminf(g.z - ax, g.w - ay));
      if (dmin > EPS9) insert(eval_inbox(a));
      // out-of-box a>=256 never reaches top-13: 256 pass-1 keys dominate.
    }
  }

  // per-wave top-13 extraction (keys unique), cross-wave merge by wave 0
  unsigned long long wres = 0ULL;
#pragma unroll
  for (int r = 0; r < TK; ++r) {
    unsigned long long w = wmax64(l[0]);
    if (lane == r) wres = w;
    if (l[0] == w) {
#pragma unroll
      for (int j = 0; j < TK - 1; ++j) l[j] = l[j + 1];
      l[TK - 1] = 0ULL;
    }
  }
  if (lane < TK) sk[wid * TK + lane] = wres;
  __syncthreads();

  if (wid == 0) {
    unsigned long long c = (lane < 4 * TK) ? sk[lane] : 0ULL;
    unsigned long long res = 0ULL;
#pragma unroll
    for (int r = 0; r < TK; ++r) {
      unsigned long long w = wmax64(c);
      if (lane == r) res = w;
      if (c == w) c = 0ULL;
    }
    if (lane < TK) {
      unsigned a = ~(unsigned)res;
      float2 an = anc2[a];
      float dmin = fminf(fminf(an.x - g.x, an.y - g.y), fminf(g.z - an.x, g.w - an.y));
      // mask_topk * mask_in_gts (mask_gt handled by early return)
      topk_idx[row * TK + lane] = (dmin > EPS9) ? (int)a : -1;
    }
  }
}

// ============ Node B: per-batch resolve, pos maxima in LDS ============
// One block per batch. LDS per-anchor {cnt<<16 | m-sum} built from the 832
// list entries; 64 gts staged in LDS; single-gt inline CIoU; multi-gt via
// wave ballot argmax over all 64 gts (first-max key (fbits(ov)<<6)|(63-m)).
// pos_align/pos_overlaps as LDS atomicMax (block == whole batch), so norm
// is computed here too. Emits packed u64 {nrm | fg<<24|lab<<8|tgt} per anchor.
__global__ __launch_bounds__(BTH)
void k_resolveB(const float* __restrict__ pd_scores,
                const float* __restrict__ pd_bboxes,
                const int* __restrict__ gt_labels,
                const float* __restrict__ gt_bboxes,
                const int* __restrict__ topk_idx,
                unsigned long long* __restrict__ pk)
{
  int b = blockIdx.x;
  int tid = threadIdx.x, lane = tid & 63;
  __shared__ unsigned int cntm[A_TOT];          // (cnt<<16) | sum(m)
  __shared__ float4 sg[MGT];
  __shared__ float  sga[MGT], sarea[MGT];
  __shared__ int    slabm[MGT];
  __shared__ unsigned int spal[MGT], spov[MGT];

  for (int i = tid; i < A_TOT; i += BTH) cntm[i] = 0u;
  if (tid < MGT) {
    float4 g = ((const float4*)gt_bboxes)[b * MGT + tid];
    sg[tid] = g;
    sga[tid] = atanf((g.z - g.x) / (g.w - g.y + EPS7));
    sarea[tid] = (g.z - g.x) * (g.w - g.y + EPS7);
    slabm[tid] = gt_labels[b * MGT + tid];
    spal[tid] = 0u; spov[tid] = 0u;
  }
  __syncthreads();

  if (tid < MGT * TK) {                 // 832 entries, one thread each
    int a = topk_idx[b * MGT * TK + tid];
    if (a >= 0) atomicAdd(&cntm[a], (1u << 16) | (unsigned)(tid / TK));
  }
  __syncthreads();

  const float4* pb = (const float4*)pd_bboxes + (size_t)b * A_TOT;
  const float*  ps = pd_scores + (size_t)b * A_TOT * NCLS;

  int   rtgt[NIT];                      // static-indexed via full unroll
  float ram[NIT];

#pragma unroll
  for (int it = 0; it < NIT; ++it) {
    int a = tid + it * BTH;
    bool valid = a < A_TOT;
    unsigned cm = valid ? cntm[a] : 0u;
    int cnt = (int)(cm >> 16);
    float4 p = make_float4(0.f, 0.f, 0.f, 0.f);
    float pa = 0.f;
    if (valid && cnt > 0) {
      p = pb[a];
      pa = atanf((p.z - p.x) / (p.w - p.y + EPS7));
    }
    int mytgt = -1; float myam = 0.f;
    if (valid && cnt == 1) {
      int m = (int)(cm & 0xffffu);
      float4 g = sg[m];
      float ov = ciou_clip(g.x, g.y, g.z, g.w, sga[m], sarea[m],
                           p.x, p.y, p.z, p.w, pa);
      float o2 = ov * ov;
      myam = ps[(size_t)a * NCLS + slabm[m]] * (o2 * o2 * o2);
      mytgt = m;
      atomicMax(&spal[m], __float_as_uint(myam));
      atomicMax(&spov[m], __float_as_uint(ov));
    }
    // multi-gt anchors: whole-wave argmax over ALL 64 gts (first-max)
    unsigned long long mb = __ballot(valid && cnt > 1);
    while (mb) {
      int src = __ffsll(mb) - 1; mb &= mb - 1;
      int   aa  = __shfl(a, src);
      float px1 = __shfl(p.x, src), py1 = __shfl(p.y, src);
      float px2 = __shfl(p.z, src), py2 = __shfl(p.w, src);
      float spa = __shfl(pa, src);
      float4 g = sg[lane];
      float ov = ciou_clip(g.x, g.y, g.z, g.w, sga[lane], sarea[lane],
                           px1, py1, px2, py2, spa);
      unsigned long long key =
          (((unsigned long long)__float_as_uint(ov)) << 6) | (unsigned)(63 - lane);
      unsigned long long w = wmax64(key);
      int   wl  = 63 - (int)(w & 63ULL);
      float wov = __uint_as_float((unsigned)(w >> 6));
      float am_s = 0.f;
      if (lane == wl) {                 // winner lane: its own gt data
        float o2 = wov * wov;
        am_s = ps[(size_t)aa * NCLS + slabm[wl]] * (o2 * o2 * o2);
        atomicMax(&spal[wl], __float_as_uint(am_s));
        atomicMax(&spov[wl], __float_as_uint(wov));
      }
      am_s = __shfl(am_s, wl);
      if (lane == src) { mytgt = wl; myam = am_s; }
    }
    rtgt[it] = mytgt; ram[it] = myam;
  }
  __syncthreads();                      // pos maxima complete (batch-wide)

#pragma unroll
  for (int it = 0; it < NIT; ++it) {
    int a = tid + it * BTH;
    if (a >= A_TOT) continue;
    int mytgt = rtgt[it];
    bool fg = mytgt >= 0;
    int tgt = fg ? mytgt : 0;
    int lab = slabm[tgt]; if (lab < 0) lab = 0;
    float nrm = 0.f;
    if (fg) {
      float pal = __uint_as_float(spal[tgt]);
      float pov = __uint_as_float(spov[tgt]);
      nrm = ram[it] * pov / (pal + EPS9);
    }
    unsigned lo = (unsigned)tgt | ((unsigned)lab << 8) | ((fg ? 1u : 0u) << 24);
    pk[(size_t)b * A_TOT + a] =
        (((unsigned long long)__float_as_uint(nrm)) << 32) | lo;
  }
}

// ============ Node C: streaming output write ============
__global__ __launch_bounds__(256)
void k_writeC(const unsigned long long* __restrict__ pk,
              const float* __restrict__ gt_bboxes,
              float* __restrict__ out, int total)
{
  __shared__ int   slab[256];
  __shared__ float snorm[256];
  int base = blockIdx.x * 256, tid = threadIdx.x;
  int t = base + tid;
  int nrows = total - base; if (nrows > 256) nrows = 256;
  size_t OFF_BOX = (size_t)total;
  size_t OFF_SCR = OFF_BOX + (size_t)total * 4;
  size_t OFF_FG  = OFF_SCR + (size_t)total * NCLS;
  size_t OFF_TGT = OFF_FG + (size_t)total;
  int lab = 0; float nrm = 0.f;
  if (t < total) {
    unsigned long long v = pk[t];
    unsigned lo = (unsigned)v;
    int tgt = (int)(lo & 0xffu);
    lab = (int)((lo >> 8) & 0xffu);
    bool fg = (lo >> 24) & 1u;
    nrm = __uint_as_float((unsigned)(v >> 32));  // 0 for bg (packed by B)
    int b = t / A_TOT;
    float4 box = ((const float4*)gt_bboxes)[b * MGT + tgt];
    out[t] = (float)lab;
    ((float4*)(out + OFF_BOX))[t] = box;
    out[OFF_FG + t]  = fg ? 1.f : 0.f;
    out[OFF_TGT + t] = (float)tgt;
  }
  slab[tid]  = lab;
  snorm[tid] = nrm;
  __syncthreads();
  float4* srow = (float4*)(out + OFF_SCR + (size_t)base * NCLS);
  int nvec = nrows * (NCLS / 4);
  for (int u = tid; u < nvec; u += 256) {
    int i  = u / (NCLS / 4);
    int c0 = (u - i * (NCLS / 4)) * 4;
    int lb = slab[i]; float nv = snorm[i];
    float4 v;
    v.x = (lb == c0    ) ? nv : 0.f;
    v.y = (lb == c0 + 1) ? nv : 0.f;
    v.z = (lb == c0 + 2) ? nv : 0.f;
    v.w = (lb == c0 + 3) ? nv : 0.f;
    srow[u] = v;
  }
}

extern "C" void kernel_launch(void* const* d_in, const int* in_sizes, int n_in,
                              void* d_out, int out_size, void* d_ws, size_t ws_size,
                              hipStream_t stream)
{
  const float* pd_scores = (const float*)d_in[0];
  const float* pd_bboxes = (const float*)d_in[1];
  const float* anc       = (const float*)d_in[2];
  const int*   gt_labels = (const int*)d_in[3];
  const float* gt_bboxes = (const float*)d_in[4];
  const float* mask_gt   = (const float*)d_in[5];
  int bs = in_sizes[0] / (A_TOT * NCLS);
  int NA = bs * A_TOT, NM = bs * MGT;

  // workspace: everything fully written before read -> no memset node
  unsigned long long* pk = (unsigned long long*)d_ws;     // NA (8B-aligned)
  int* topk_idx = (int*)(pk + NA);                        // NM*TK

  k_topkA<<<NM, 256, 0, stream>>>(pd_scores, pd_bboxes, anc, gt_labels,
                                  gt_bboxes, mask_gt, topk_idx);
  k_resolveB<<<bs, BTH, 0, stream>>>(pd_scores, pd_bboxes, gt_labels,
                                     gt_bboxes, topk_idx, pk);
  k_writeC<<<(NA + 255) / 256, 256, 0, stream>>>(pk, gt_bboxes,
                                                 (float*)d_out, NA);
}

// Round 10
// 124.631 us; speedup vs baseline: 2.2627x; 1.1026x over previous
//
#include <hip/hip_runtime.h>

#define A_TOT 8400
#define NCLS  80
#define MGT   64
#define TK    13
#define EPS7  1e-7f
#define EPS9  1e-9f
#define INV_PI2 0.4052847345693511f     // 4/pi^2
#define BTH   1024                      // k_resolveB threads / anchor window
#define NWIN  ((A_TOT + BTH - 1) / BTH) // 9 windows per batch

__device__ __forceinline__ float ciou_clip(
    float gx1, float gy1, float gx2, float gy2, float ga, float area1,
    float px1, float py1, float px2, float py2, float pa)
{
  float w2 = px2 - px1, h2 = py2 - py1 + EPS7;
  float iw = fmaxf(fminf(gx2, px2) - fmaxf(gx1, px1), 0.f);
  float ih = fmaxf(fminf(gy2, py2) - fmaxf(gy1, py1), 0.f);
  float inter = iw * ih;
  float uni = area1 + w2 * h2 - inter + EPS7;
  float iou = inter / uni;
  float cw = fmaxf(gx2, px2) - fminf(gx1, px1);
  float ch = fmaxf(gy2, py2) - fminf(gy1, py1);
  float c2 = cw * cw + ch * ch + EPS7;
  float dx = px1 + px2 - gx1 - gx2;
  float dy = py1 + py2 - gy1 - gy2;
  float rho2 = (dx * dx + dy * dy) * 0.25f;
  float dd = pa - ga;
  float v = INV_PI2 * dd * dd;
  float alpha = v / (v - iou + (1.f + EPS7));
  float c = iou - (rho2 / c2 + v * alpha);
  return fmaxf(c, 0.f);   // overlaps = ciou.clip(0)
}

__device__ __forceinline__ unsigned long long wmax64(unsigned long long k) {
#pragma unroll
  for (int s = 32; s > 0; s >>= 1) {
    unsigned long long o = __shfl_xor(k, s, 64);
    k = (o > k) ? o : k;
  }
  return k;
}

// ============ Node A: per-(b,m) top-13 -> dense index lists ============
// Also zeroes its OWN pos_al/pos_ov slot (next dispatch reads them) -> no
// memset node anywhere. Candidate set = {anchors 0..255} U {in-box grid
// rectangles per scale}; provably contains lax.top_k(metrics,13) (round-5
// argument: positives lie in the rectangles, zero-metric tie-fills are the
// smallest-index anchors and the 256 pass-1 keys dominate all excluded ones).
__global__ __launch_bounds__(256)
void k_topkA(const float* __restrict__ pd_scores,
             const float* __restrict__ pd_bboxes,
             const float* __restrict__ anc,
             const int* __restrict__ gt_labels,
             const float* __restrict__ gt_bboxes,
             const float* __restrict__ mask_gt,
             int* __restrict__ topk_idx,
             unsigned int* __restrict__ pos_al,
             unsigned int* __restrict__ pos_ov)
{
  int row = blockIdx.x;                 // b*MGT + m
  int tid = threadIdx.x, lane = tid & 63, wid = tid >> 6;
  __shared__ unsigned long long sk[4 * TK];

  if (tid == 0) { pos_al[row] = 0u; pos_ov[row] = 0u; }  // own slot only

  if (mask_gt[row] <= 0.f) {            // block-uniform
    if (tid < TK) topk_idx[row * TK + tid] = -1;
    return;
  }
  int b = row >> 6;

  float4 g = ((const float4*)gt_bboxes)[row];
  float ga = atanf((g.z - g.x) / (g.w - g.y + EPS7));
  float area1 = (g.z - g.x) * (g.w - g.y + EPS7);
  int label = gt_labels[row];
  const float*  ps   = pd_scores + (size_t)b * A_TOT * NCLS + label;
  const float4* pb   = (const float4*)(pd_bboxes + (size_t)b * A_TOT * 4);
  const float2* anc2 = (const float2*)anc;

  unsigned long long l[TK];
#pragma unroll
  for (int k = 0; k < TK; ++k) l[k] = 0ULL;

  auto insert = [&](unsigned long long key) {
    if (key > l[TK - 1]) {
#pragma unroll
      for (int j = TK - 1; j > 0; --j) {
        unsigned long long prev = l[j - 1];
        l[j] = (key > prev) ? prev : ((key > l[j]) ? key : l[j]);
      }
      l[0] = (key > l[0]) ? key : l[0];
    }
  };
  auto eval_inbox = [&](int a) -> unsigned long long {
    float4 p = pb[a];
    float pa = atanf((p.z - p.x) / (p.w - p.y + EPS7));
    float ov = ciou_clip(g.x, g.y, g.z, g.w, ga, area1, p.x, p.y, p.z, p.w, pa);
    float o2 = ov * ov;
    float metric = ps[(size_t)a * NCLS] * (o2 * o2 * o2);
    return (((unsigned long long)__float_as_uint(metric)) << 32) |
           (unsigned long long)(~(unsigned)a);
  };

  // pass 1: anchors 0..255 (zero-pool for tie-fills; covers rect cells < 256)
  {
    int a = tid;
    float2 an = anc2[a];
    float dmin = fminf(fminf(an.x - g.x, an.y - g.y), fminf(g.z - an.x, g.w - an.y));
    unsigned long long key = (unsigned long long)(~(unsigned)a);
    if (dmin > EPS9) key = eval_inbox(a);
    insert(key);
  }

  // pass 2: per-scale in-box rectangles (closed form; skip a<256)
  const int   ns[3] = {80, 40, 20};
  const float ss[3] = {8.f, 16.f, 32.f};
  const int   bb[3] = {0, 6400, 8000};
#pragma unroll
  for (int sc = 0; sc < 3; ++sc) {
    int n = ns[sc]; float s = ss[sc]; int base = bb[sc];
    float inv_s = 1.f / s;              // power of two: exact
    int xlo = max(0,     (int)floorf(g.x * inv_s - 0.5f));
    int xhi = min(n - 1, (int)ceilf (g.z * inv_s - 0.5f));
    int ylo = max(0,     (int)floorf(g.y * inv_s - 0.5f));
    int yhi = min(n - 1, (int)ceilf (g.w * inv_s - 0.5f));
    int nx = xhi - xlo + 1, ny = yhi - ylo + 1;
    if (nx <= 0 || ny <= 0) continue;
    int tot = nx * ny;
    float invnx = 1.f / (float)nx;
    for (int r = tid; r < tot; r += 256) {
      int q  = (int)floorf(((float)r + 0.5f) * invnx);
      int ix = xlo + (r - q * nx);
      int iy = ylo + q;
      int a = base + iy * n + ix;
      if (a < 256) continue;
      float ax = ((float)ix + 0.5f) * s;
      float ay = ((float)iy + 0.5f) * s;
      float dmin = fminf(fminf(ax - g.x, ay - g.y), fminf(g.z - ax, g.w - ay));
      if (dmin > EPS9) insert(eval_inbox(a));
      // out-of-box a>=256 never reaches top-13: 256 pass-1 keys dominate.
    }
  }

  // per-wave top-13 extraction (keys unique), cross-wave merge by wave 0
  unsigned long long wres = 0ULL;
#pragma unroll
  for (int r = 0; r < TK; ++r) {
    unsigned long long w = wmax64(l[0]);
    if (lane == r) wres = w;
    if (l[0] == w) {
#pragma unroll
      for (int j = 0; j < TK - 1; ++j) l[j] = l[j + 1];
      l[TK - 1] = 0ULL;
    }
  }
  if (lane < TK) sk[wid * TK + lane] = wres;
  __syncthreads();

  if (wid == 0) {
    unsigned long long c = (lane < 4 * TK) ? sk[lane] : 0ULL;
    unsigned long long res = 0ULL;
#pragma unroll
    for (int r = 0; r < TK; ++r) {
      unsigned long long w = wmax64(c);
      if (lane == r) res = w;
      if (c == w) c = 0ULL;
    }
    if (lane < TK) {
      unsigned a = ~(unsigned)res;
      float2 an = anc2[a];
      float dmin = fminf(fminf(an.x - g.x, an.y - g.y), fminf(g.z - an.x, g.w - an.y));
      // mask_topk * mask_in_gts (mask_gt handled by early return)
      topk_idx[row * TK + lane] = (dmin > EPS9) ? (int)a : -1;
    }
  }
}

// ============ Node B: windowed anchor-parallel resolve ============
// Grid = bs * NWIN blocks; block (b, s) owns anchors [s*BTH, s*BTH+BTH).
// Scans the batch's 832 list entries (1 thread each), scatters in-window
// hits into a 4KB LDS count map, then resolves ONE anchor per thread:
// cnt==1 inline CIoU; cnt>1 whole-wave ballot argmax over all 64 LDS-staged
// gts (first-max key (fbits(ov)<<6)|(63-m)). pos maxima via global
// atomicMax (slots pre-zeroed by node A). Emits pk = {am | fg|lab|tgt}.
__global__ __launch_bounds__(BTH)
void k_resolveB(const float* __restrict__ pd_scores,
                const float* __restrict__ pd_bboxes,
                const int* __restrict__ gt_labels,
                const float* __restrict__ gt_bboxes,
                const int* __restrict__ topk_idx,
                unsigned int* __restrict__ pos_al,
                unsigned int* __restrict__ pos_ov,
                unsigned long long* __restrict__ pk)
{
  int b = blockIdx.x / NWIN;
  int s = blockIdx.x - b * NWIN;
  int lo = s * BTH;
  int tid = threadIdx.x, lane = tid & 63;

  __shared__ unsigned int cntm[BTH];            // (cnt<<16) | sum(m)
  __shared__ float4 sg[MGT];
  __shared__ float  sga[MGT], sarea[MGT];
  __shared__ int    slabm[MGT];

  cntm[tid] = 0u;
  if (tid < MGT) {
    float4 g = ((const float4*)gt_bboxes)[b * MGT + tid];
    sg[tid] = g;
    sga[tid] = atanf((g.z - g.x) / (g.w - g.y + EPS7));
    sarea[tid] = (g.z - g.x) * (g.w - g.y + EPS7);
    slabm[tid] = gt_labels[b * MGT + tid];
  }
  __syncthreads();

  if (tid < MGT * TK) {                 // 832 entries, one thread each
    int a = topk_idx[b * MGT * TK + tid];
    int r = a - lo;
    if (a >= 0 && r >= 0 && r < BTH)
      atomicAdd(&cntm[r], (1u << 16) | (unsigned)(tid / TK));
  }
  __syncthreads();

  const float4* pb = (const float4*)pd_bboxes + (size_t)b * A_TOT;
  const float*  ps = pd_scores + (size_t)b * A_TOT * NCLS;

  int a = lo + tid;
  bool valid = a < A_TOT;
  unsigned cm = valid ? cntm[tid] : 0u;
  int cnt = (int)(cm >> 16);
  float4 p = make_float4(0.f, 0.f, 0.f, 0.f);
  float pa = 0.f;
  if (valid && cnt > 0) {
    p = pb[a];
    pa = atanf((p.z - p.x) / (p.w - p.y + EPS7));
  }
  int mytgt = -1; float myam = 0.f;
  if (valid && cnt == 1) {
    int m = (int)(cm & 0xffffu);
    float4 g = sg[m];
    float ov = ciou_clip(g.x, g.y, g.z, g.w, sga[m], sarea[m],
                         p.x, p.y, p.z, p.w, pa);
    float o2 = ov * ov;
    myam = ps[(size_t)a * NCLS + slabm[m]] * (o2 * o2 * o2);
    mytgt = m;
    atomicMax(pos_al + b * MGT + m, __float_as_uint(myam));
    atomicMax(pos_ov + b * MGT + m, __float_as_uint(ov));
  }
  // multi-gt anchors: whole-wave argmax over ALL 64 gts (first-max)
  unsigned long long mb = __ballot(valid && cnt > 1);
  while (mb) {
    int src = __ffsll(mb) - 1; mb &= mb - 1;
    int   aa  = __shfl(a, src);
    float px1 = __shfl(p.x, src), py1 = __shfl(p.y, src);
    float px2 = __shfl(p.z, src), py2 = __shfl(p.w, src);
    float spa = __shfl(pa, src);
    float4 g = sg[lane];
    float ov = ciou_clip(g.x, g.y, g.z, g.w, sga[lane], sarea[lane],
                         px1, py1, px2, py2, spa);
    unsigned long long key =
        (((unsigned long long)__float_as_uint(ov)) << 6) | (unsigned)(63 - lane);
    unsigned long long w = wmax64(key);
    int   wl  = 63 - (int)(w & 63ULL);
    float wov = __uint_as_float((unsigned)(w >> 6));
    float am_s = 0.f;
    if (lane == wl) {                   // winner lane: its own gt data
      float o2 = wov * wov;
      am_s = ps[(size_t)aa * NCLS + slabm[wl]] * (o2 * o2 * o2);
      atomicMax(pos_al + b * MGT + wl, __float_as_uint(am_s));
      atomicMax(pos_ov + b * MGT + wl, __float_as_uint(wov));
    }
    am_s = __shfl(am_s, wl);
    if (lane == src) { mytgt = wl; myam = am_s; }
  }

  if (valid) {
    bool fg = mytgt >= 0;
    int tgt = fg ? mytgt : 0;
    int lab = slabm[tgt]; if (lab < 0) lab = 0;
    unsigned lov = (unsigned)tgt | ((unsigned)lab << 8) | ((fg ? 1u : 0u) << 24);
    pk[(size_t)b * A_TOT + a] =
        (((unsigned long long)__float_as_uint(myam)) << 32) | lov;
  }
}

// ============ Node C: norm + streaming output write ============
__global__ __launch_bounds__(256)
void k_writeC(const unsigned long long* __restrict__ pk,
              const unsigned int* __restrict__ pos_al,
              const unsigned int* __restrict__ pos_ov,
              const float* __restrict__ gt_bboxes,
              float* __restrict__ out, int total)
{
  __shared__ int   slab[256];
  __shared__ float snorm[256];
  int base = blockIdx.x * 256, tid = threadIdx.x;
  int t = base + tid;
  int nrows = total - base; if (nrows > 256) nrows = 256;
  size_t OFF_BOX = (size_t)total;
  size_t OFF_SCR = OFF_BOX + (size_t)total * 4;
  size_t OFF_FG  = OFF_SCR + (size_t)total * NCLS;
  size_t OFF_TGT = OFF_FG + (size_t)total;
  int lab = 0; float nrm = 0.f;
  if (t < total) {
    unsigned long long v = pk[t];
    unsigned lov = (unsigned)v;
    int tgt = (int)(lov & 0xffu);
    lab = (int)((lov >> 8) & 0xffu);
    bool fg = (lov >> 24) & 1u;
    int b = t / A_TOT;
    int gi = b * MGT + tgt;
    if (fg) {
      float am  = __uint_as_float((unsigned)(v >> 32));
      float pal = __uint_as_float(pos_al[gi]);
      float pov = __uint_as_float(pos_ov[gi]);
      nrm = am * pov / (pal + EPS9);    // pos tables are tiny -> L2-resident
    }
    float4 box = ((const float4*)gt_bboxes)[gi];
    out[t] = (float)lab;
    ((float4*)(out + OFF_BOX))[t] = box;
    out[OFF_FG + t]  = fg ? 1.f : 0.f;
    out[OFF_TGT + t] = (float)tgt;
  }
  slab[tid]  = lab;
  snorm[tid] = nrm;
  __syncthreads();
  float4* srow = (float4*)(out + OFF_SCR + (size_t)base * NCLS);
  int nvec = nrows * (NCLS / 4);
  for (int u = tid; u < nvec; u += 256) {
    int i  = u / (NCLS / 4);
    int c0 = (u - i * (NCLS / 4)) * 4;
    int lb = slab[i]; float nv = snorm[i];
    float4 v;
    v.x = (lb == c0    ) ? nv : 0.f;
    v.y = (lb == c0 + 1) ? nv : 0.f;
    v.z = (lb == c0 + 2) ? nv : 0.f;
    v.w = (lb == c0 + 3) ? nv : 0.f;
    srow[u] = v;
  }
}

extern "C" void kernel_launch(void* const* d_in, const int* in_sizes, int n_in,
                              void* d_out, int out_size, void* d_ws, size_t ws_size,
                              hipStream_t stream)
{
  const float* pd_scores = (const float*)d_in[0];
  const float* pd_bboxes = (const float*)d_in[1];
  const float* anc       = (const float*)d_in[2];
  const int*   gt_labels = (const int*)d_in[3];
  const float* gt_bboxes = (const float*)d_in[4];
  const float* mask_gt   = (const float*)d_in[5];
  int bs = in_sizes[0] / (A_TOT * NCLS);
  int NA = bs * A_TOT, NM = bs * MGT;

  // workspace: every word written before read -> no memset node
  unsigned long long* pk = (unsigned long long*)d_ws;     // NA (8B-aligned)
  int* topk_idx = (int*)(pk + NA);                        // NM*TK
  unsigned int* pos_al = (unsigned int*)(topk_idx + NM * TK);  // NM
  unsigned int* pos_ov = pos_al + NM;                     // NM

  k_topkA<<<NM, 256, 0, stream>>>(pd_scores, pd_bboxes, anc, gt_labels,
                                  gt_bboxes, mask_gt, topk_idx, pos_al, pos_ov);
  k_resolveB<<<bs * NWIN, BTH, 0, stream>>>(pd_scores, pd_bboxes, gt_labels,
                                            gt_bboxes, topk_idx, pos_al,
                                            pos_ov, pk);
  k_writeC<<<(NA + 255) / 256, 256, 0, stream>>>(pk, pos_al, pos_ov, gt_bboxes,
                                                 (float*)d_out, NA);
}